// Round 6
// baseline (1725.903 us; speedup 1.0000x reference)
//
#include <hip/hip_runtime.h>
#include <hip/hip_bf16.h>
#include <math.h>

typedef short s16x8 __attribute__((ext_vector_type(8)));
typedef short s16x4 __attribute__((ext_vector_type(4)));
typedef float f32x4 __attribute__((ext_vector_type(4)));

#define MFMA(A,B,C) __builtin_amdgcn_mfma_f32_16x16x32_bf16((A),(B),(C),0,0,0)

__device__ __forceinline__ float bf2f(short u){
  unsigned int x = ((unsigned int)(unsigned short)u) << 16;
  return __builtin_bit_cast(float, x);
}
__device__ __forceinline__ short f2bf(float f){
  unsigned int x = __builtin_bit_cast(unsigned int, f);
  x += 0x7fffu + ((x >> 16) & 1u);
  return (short)(x >> 16);
}
// tanh-form gelu, overflow-safe
__device__ __forceinline__ float gelu_t(float x){
  float u = x + 0.044715f*x*x*x;
  float e = __expf(1.5957691216057308f*u);
  float th = 1.f - 2.f/(e + 1.f);
  return 0.5f*x*(1.f + th);
}

// bijective XCD-chunk swizzle (m204 formula)
__device__ __forceinline__ void xcd_swz(int gx, int gy, int &bx, int &by){
  int id = bx + by*gx;
  int nwg = gx*gy;
  int q = nwg >> 3, r = nwg & 7;
  int xcd = id & 7, idx = id >> 3;
  int nid = (xcd < r ? xcd*(q+1) : r*(q+1) + (xcd-r)*q) + idx;
  bx = nid % gx; by = nid / gx;
}

#define FFI 1365
#define FFIP 1376

// ============ weights-stationary GEMM: B panel (64 cols) in LDS once per chunk, A streamed ============
// C[M][N] = A[M][KstA-ish] * Bt[N][KstB]^T ; block = 4 waves, tile (MF*64) x 64
template<int MF, int KSTEPS, int NKC, int HAS_BIAS, int HAS_RES, int OUT_F32, int OUT_BF16>
__global__ __launch_bounds__(256) void gemm_s(
    const short* __restrict__ A, const short* __restrict__ Bt,
    const float* __restrict__ bias, const float* __restrict__ res,
    float* __restrict__ outF, short* __restrict__ outB,
    int N, int KstA, int KstB)
{
  constexpr int K4 = KSTEPS*4;     // 16B slots per LDS row
  constexpr int BKC = KSTEPS*32;   // K elems per chunk
  __shared__ short Bs[64*K4*8];
  const int tid = threadIdx.x;
  const int lane = tid & 63, wv = tid >> 6;
  const int g = lane >> 4, qi = lane & 15;
  int bx = blockIdx.x, by = blockIdx.y;
  xcd_swz(gridDim.x, gridDim.y, bx, by);
  const int m0 = bx * (MF*64), n0 = by * 64;

  const short* Ap = A + (size_t)(m0 + wv*(MF*16) + qi)*KstA + g*8;

  f32x4 acc[MF][4];
  #pragma unroll
  for (int i=0;i<MF;i++)
    #pragma unroll
    for (int j=0;j<4;j++) acc[i][j] = (f32x4){0.f,0.f,0.f,0.f};

  s16x8 a0[MF], a1[MF], a2[MF], a3[MF];

  for (int kc=0; kc<NKC; ++kc){
    if (kc) __syncthreads();
    // ---- stage B chunk into LDS, XOR-swizzled (write-side + read-side) ----
    #pragma unroll
    for (int p=0; p<KSTEPS; ++p){
      int slot = p*256 + tid;
      int r = slot / K4;
      int s = slot & (K4-1);
      s16x8 v = *(const s16x8*)(Bt + (size_t)(n0+r)*KstB + kc*BKC + s*8);
      *(s16x8*)&Bs[((r*K4) + (s^(r&7)))*8] = v;
    }
    const short* Apc = Ap + kc*BKC;
    auto LOADA = [&](s16x8 (&buf)[MF], int kk){
      #pragma unroll
      for (int mf=0; mf<MF; ++mf)
        buf[mf] = *(const s16x8*)(Apc + (size_t)mf*16*KstA + kk*32);
    };
    LOADA(a0,0); LOADA(a1,1); LOADA(a2,2); LOADA(a3,3);
    __syncthreads();
    auto STEP = [&](s16x8 (&buf)[MF], int kk){
      s16x8 bf[4];
      #pragma unroll
      for (int nf=0; nf<4; ++nf)
        bf[nf] = *(const s16x8*)&Bs[(((nf*16+qi)*K4) + ((kk*4+g)^(qi&7)))*8];
      #pragma unroll
      for (int mf=0; mf<MF; ++mf)
        #pragma unroll
        for (int nf=0; nf<4; ++nf)
          acc[mf][nf] = MFMA(buf[mf], bf[nf], acc[mf][nf]);
      if (kk+4 < KSTEPS) LOADA(buf, kk+4);
    };
    #pragma unroll
    for (int kk=0; kk<KSTEPS; kk+=4){
      STEP(a0,kk); STEP(a1,kk+1); STEP(a2,kk+2); STEP(a3,kk+3);
    }
  }
  #pragma unroll
  for (int mf=0; mf<MF; ++mf){
    #pragma unroll
    for (int rr=0; rr<4; ++rr){
      int row = m0 + wv*(MF*16) + mf*16 + g*4 + rr;
      #pragma unroll
      for (int nf=0; nf<4; ++nf){
        int col = n0 + nf*16 + qi;
        float v = acc[mf][nf][rr];
        if (HAS_BIAS) v += bias[col];
        if (HAS_RES)  v += res[(size_t)row*N + col];
        if (OUT_F32)  outF[(size_t)row*N + col] = v;
        if (OUT_BF16) outB[(size_t)row*N + col] = f2bf(v);
      }
    }
  }
}

// ============ FF1 + GEGLU, weights-stationary (two 64-wide panels), BKC=256, 2 chunks ============
__global__ __launch_bounds__(256) void geglu_s(
    const short* __restrict__ A, const short* __restrict__ Bt,
    const float* __restrict__ b1, short* __restrict__ hg)
{
  constexpr int KSTEPS = 8, K4 = 32, BKC = 256;
  __shared__ short Ba[64*K4*8];
  __shared__ short Bg[64*K4*8];
  const int tid = threadIdx.x;
  const int lane = tid & 63, wv = tid >> 6;
  const int g = lane >> 4, qi = lane & 15;
  int bx = blockIdx.x, by = blockIdx.y;
  xcd_swz(gridDim.x, gridDim.y, bx, by);
  const int m0 = bx * 256, n0 = by * 64;

  const short* Ap = A + (size_t)(m0 + wv*64 + qi)*512 + g*8;

  f32x4 aa[4][4], ag[4][4];
  #pragma unroll
  for (int i=0;i<4;i++)
    #pragma unroll
    for (int j=0;j<4;j++){ aa[i][j]=(f32x4){0.f,0.f,0.f,0.f}; ag[i][j]=(f32x4){0.f,0.f,0.f,0.f}; }

  s16x8 a0[4], a1[4];

  for (int kc=0; kc<2; ++kc){
    if (kc) __syncthreads();
    #pragma unroll
    for (int p=0; p<KSTEPS; ++p){
      int slot = p*256 + tid;
      int r = slot / K4;
      int s = slot & (K4-1);
      int ra = min(n0 + r, FFI-1);
      int rg = min(FFI + n0 + r, 2729);
      s16x8 va = *(const s16x8*)(Bt + (size_t)ra*512 + kc*BKC + s*8);
      s16x8 vg = *(const s16x8*)(Bt + (size_t)rg*512 + kc*BKC + s*8);
      int sw = ((r*K4) + (s^(r&7)))*8;
      *(s16x8*)&Ba[sw] = va;
      *(s16x8*)&Bg[sw] = vg;
    }
    const short* Apc = Ap + kc*BKC;
    auto LOADA = [&](s16x8 (&buf)[4], int kk){
      #pragma unroll
      for (int mf=0; mf<4; ++mf)
        buf[mf] = *(const s16x8*)(Apc + (size_t)mf*16*512 + kk*32);
    };
    LOADA(a0,0); LOADA(a1,1);
    __syncthreads();
    auto STEP = [&](s16x8 (&buf)[4], int kk){
      s16x8 ba[4], bg[4];
      #pragma unroll
      for (int nf=0; nf<4; ++nf){
        int off = (((nf*16+qi)*K4) + ((kk*4+g)^(qi&7)))*8;
        ba[nf] = *(const s16x8*)&Ba[off];
        bg[nf] = *(const s16x8*)&Bg[off];
      }
      #pragma unroll
      for (int mf=0; mf<4; ++mf)
        #pragma unroll
        for (int nf=0; nf<4; ++nf){
          aa[mf][nf] = MFMA(buf[mf], ba[nf], aa[mf][nf]);
          ag[mf][nf] = MFMA(buf[mf], bg[nf], ag[mf][nf]);
        }
      if (kk+2 < KSTEPS) LOADA(buf, kk+2);
    };
    #pragma unroll
    for (int kk=0; kk<KSTEPS; kk+=2){
      STEP(a0,kk); STEP(a1,kk+1);
    }
  }
  #pragma unroll
  for (int mf=0; mf<4; ++mf){
    #pragma unroll
    for (int rr=0; rr<4; ++rr){
      int row = m0 + wv*64 + mf*16 + g*4 + rr;
      #pragma unroll
      for (int nf=0; nf<4; ++nf){
        int col = n0 + nf*16 + qi;
        if (col < FFI){
          float va = aa[mf][nf][rr] + b1[col];
          float vg = ag[mf][nf][rr] + b1[FFI+col];
          hg[(size_t)row*FFIP + col] = f2bf(va * gelu_t(vg));
        } else if (col < FFIP){
          hg[(size_t)row*FFIP + col] = 0;
        }
      }
    }
  }
}

// ---------------- rotary/xpos tables (f64 precompute) ----------------
__global__ void rope_k(float* __restrict__ tab){
  int n = blockIdx.x, dd = threadIdx.x;
  int i = dd & 31;
  double invf = pow(10000.0, -(double)i/32.0);
  double fr = (double)n * invf;
  double c = cos(fr), s = sin(fr);
  double sv = (2.0*i + 25.6)/89.6;
  double pw = ((double)n - 4096.0)/128.0;
  double xs = pow(sv, pw);
  size_t o = (size_t)n*64 + dd;
  tab[o]            = (float)(c*xs);
  tab[524288+o]     = (float)(s*xs);
  tab[2*524288+o]   = (float)(c/xs);
  tab[3*524288+o]   = (float)(s/xs);
}

// ---------------- weight transpose+cast: dst[N][Kp] bf16 from src[K][N] f32 ----------------
__global__ __launch_bounds__(256) void wtrans_k(
    const float* __restrict__ src, short* __restrict__ dst,
    int K, int N, int Kp, long srcStride, long dstStride)
{
  __shared__ float t[64][65];
  const float* s = src + (size_t)blockIdx.z * srcStride;
  short* d = dst + (size_t)blockIdx.z * dstStride;
  int n0 = blockIdx.x*64, k0 = blockIdx.y*64;
  int tid = threadIdx.x;
  #pragma unroll
  for (int p=0;p<4;p++){
    int task = p*256+tid;
    int r = task>>4, c = (task&15)*4;
    int k = k0 + r;
    #pragma unroll
    for (int e=0;e<4;e++){
      int n = n0+c+e;
      t[r][c+e] = (k<K && n<N) ? s[(size_t)k*N+n] : 0.f;
    }
  }
  __syncthreads();
  #pragma unroll
  for (int p=0;p<2;p++){
    int task = p*256+tid;
    int nr = task>>3, kg=(task&7)*8;
    int n = n0+nr;
    if (n < N && (k0+kg) < Kp){
      s16x8 v;
      #pragma unroll
      for (int j=0;j<8;j++) v[j] = f2bf(t[kg+j][nr]);
      *(s16x8*)(d + (size_t)n*Kp + k0 + kg) = v;
    }
  }
}

// ---------------- f32 -> bf16 cast ----------------
__global__ void cast_k(const float* __restrict__ in, short* __restrict__ out){
  int i = (blockIdx.x*256+threadIdx.x)*4;
  float4 v = *(const float4*)(in+i);
  s16x4 o = { f2bf(v.x), f2bf(v.y), f2bf(v.z), f2bf(v.w) };
  *(s16x4*)(out+i) = o;
}

// ---------------- q/k: l2norm + scale + xpos rotary ----------------
__global__ __launch_bounds__(256) void qkprep_k(
    const short* __restrict__ qkv, const float* __restrict__ tab,
    const float* __restrict__ qs, const float* __restrict__ ks,
    short* __restrict__ qrot, short* __restrict__ krot)
{
  int wv = threadIdx.x >> 6, lane = threadIdx.x & 63;
  int wid = blockIdx.x*4 + wv;
  int n = wid >> 3, h = wid & 7;
  float qv = bf2f(qkv[(size_t)n*1536 + h*64 + lane]);
  float kv = bf2f(qkv[(size_t)n*1536 + 512 + h*64 + lane]);
  float sq = qv*qv, sk = kv*kv;
  #pragma unroll
  for (int m=1;m<64;m<<=1){ sq += __shfl_xor(sq,m,64); sk += __shfl_xor(sk,m,64); }
  qv *= qs[lane] / fmaxf(sqrtf(sq), 1e-12f);
  kv *= ks[lane] / fmaxf(sqrtf(sk), 1e-12f);
  float qo = __shfl_xor(qv,32,64), ko = __shfl_xor(kv,32,64);
  float sgn = (lane<32)? -1.f : 1.f;
  size_t to = (size_t)n*64 + lane;
  float cq = tab[to], sxq = tab[524288+to], ck = tab[2*524288+to], sxk = tab[3*524288+to];
  qrot[((size_t)h*8192+n)*64+lane] = f2bf(qv*cq + sgn*qo*sxq);
  krot[((size_t)h*8192+n)*64+lane] = f2bf(kv*ck + sgn*ko*sxk);
}

// ---------------- V transpose: vt[h][d][n] ----------------
__global__ __launch_bounds__(256) void vtrans_k(const short* __restrict__ qkv, short* __restrict__ vt){
  __shared__ short t[64][72];
  int n0 = blockIdx.x*64, h = blockIdx.y;
  int tid = threadIdx.x;
  #pragma unroll
  for (int p=0;p<2;p++){
    int task = p*256+tid;
    int r = task>>3, cg = (task&7)*8;
    *(s16x8*)&t[r][cg] = *(const s16x8*)(qkv + (size_t)(n0+r)*1536 + 1024 + h*64 + cg);
  }
  __syncthreads();
  #pragma unroll
  for (int p=0;p<2;p++){
    int task = p*256+tid;
    int d = task>>3, nb = (task&7)*8;
    s16x8 v;
    #pragma unroll
    for (int j=0;j<8;j++) v[j] = t[nb+j][d];
    *(s16x8*)(vt + ((size_t)h*64+d)*8192 + n0 + nb) = v;
  }
}

// ---------------- local windowed attention: 512 thr, 8 waves x 32 q-rows ----------------
__global__ __launch_bounds__(512,1) void attn_k(
    const short* __restrict__ qrot, const short* __restrict__ krot,
    const short* __restrict__ vt, short* __restrict__ attn_o)
{
  __shared__ short Ks[128][72];
  __shared__ short Vs[64][136];
  const int w = blockIdx.x, h = blockIdx.y;
  const int tid = threadIdx.x, lane = tid & 63, wv = tid >> 6;
  const int g = lane >> 4, qi = lane & 15;
  const int wq0 = wv * 32;
  s16x8 qf[2][2];
  #pragma unroll
  for (int ni=0;ni<2;ni++){
    int qg = w*256 + wq0 + ni*16 + qi;
    const short* p = qrot + ((size_t)h*8192 + qg)*64 + g*8;
    qf[ni][0] = *(const s16x8*)p;
    qf[ni][1] = *(const s16x8*)(p + 32);
  }
  f32x4 oacc[4][2];
  float mrun[2], lrun[2];
  #pragma unroll
  for (int i=0;i<2;i++){
    mrun[i] = -1e30f; lrun[i] = 0.f;
    #pragma unroll
    for (int j=0;j<4;j++) oacc[j][i]=(f32x4){0.f,0.f,0.f,0.f};
  }
  const int kvbase = w*256 - 256;
  for (int s=0;s<4;s++){
    __syncthreads();
    #pragma unroll
    for (int p=0;p<2;p++){
      int task = p*512 + tid;
      {
        int r = task>>3, cg = (task&7)*8;
        int jg = kvbase + s*128 + r;
        s16x8 v = {0,0,0,0,0,0,0,0};
        if (jg>=0) v = *(const s16x8*)(krot + ((size_t)h*8192+jg)*64 + cg);
        *(s16x8*)&Ks[r][cg] = v;
      }
      {
        int dd = task>>4, cg = (task&15)*8;
        int jg = kvbase + s*128 + cg;
        s16x8 v = {0,0,0,0,0,0,0,0};
        if (jg>=0) v = *(const s16x8*)(vt + ((size_t)h*64+dd)*8192 + jg);
        *(s16x8*)&Vs[dd][cg] = v;
      }
    }
    __syncthreads();
    for (int cc=0;cc<2;cc++){
      const int jlo = (s*2+cc)*64;
      if (jlo + 63 < wq0) continue;
      if (jlo > wq0 + 287) continue;
      if (w==0 && jlo < 256) continue;
      f32x4 sacc[4][2];
      #pragma unroll
      for (int i=0;i<4;i++)
        #pragma unroll
        for (int j=0;j<2;j++) sacc[i][j]=(f32x4){0.f,0.f,0.f,0.f};
      #pragma unroll
      for (int ks=0;ks<2;ks++){
        s16x8 kf[4];
        #pragma unroll
        for (int mi=0;mi<4;mi++) kf[mi] = *(const s16x8*)&Ks[cc*64+mi*16+qi][ks*32+g*8];
        #pragma unroll
        for (int mi=0;mi<4;mi++)
          #pragma unroll
          for (int ni=0;ni<2;ni++)
            sacc[mi][ni] = MFMA(kf[mi], qf[ni][ks], sacc[mi][ni]);
      }
      const bool interior = (jlo >= wq0+31) && (jlo+63 <= wq0+256);
      float cmax[2];
      #pragma unroll
      for (int ni=0;ni<2;ni++) cmax[ni] = -1e30f;
      #pragma unroll
      for (int mi=0;mi<4;mi++)
        #pragma unroll
        for (int ni=0;ni<2;ni++)
          #pragma unroll
          for (int r=0;r<4;r++){
            float x = sacc[mi][ni][r] * 8.f;
            if (!interior){
              int j = jlo + mi*16 + g*4 + r;
              int ql = wq0 + ni*16 + qi;
              if (j < ql || j > ql+256) x = -1e30f;
            }
            sacc[mi][ni][r] = x;
            cmax[ni] = fmaxf(cmax[ni], x);
          }
      #pragma unroll
      for (int ni=0;ni<2;ni++){
        cmax[ni] = fmaxf(cmax[ni], __shfl_xor(cmax[ni],16,64));
        cmax[ni] = fmaxf(cmax[ni], __shfl_xor(cmax[ni],32,64));
      }
      float scl[2], psum[2];
      s16x8 pf[2][2];
      #pragma unroll
      for (int ni=0;ni<2;ni++){
        float mn = fmaxf(mrun[ni], cmax[ni]);
        scl[ni] = __expf(mrun[ni]-mn);
        mrun[ni] = mn;
        float ps = 0.f;
        #pragma unroll
        for (int t=0;t<2;t++)
          #pragma unroll
          for (int hh=0; hh<2; hh++){
            int mi = 2*t+hh;
            #pragma unroll
            for (int r=0;r<4;r++){
              float pv = __expf(sacc[mi][ni][r]-mn);
              ps += pv;
              pf[t][ni][hh*4+r] = f2bf(pv);
            }
          }
        psum[ni]=ps;
      }
      #pragma unroll
      for (int ni=0;ni<2;ni++){
        psum[ni] += __shfl_xor(psum[ni],16,64);
        psum[ni] += __shfl_xor(psum[ni],32,64);
        lrun[ni] = lrun[ni]*scl[ni] + psum[ni];
        #pragma unroll
        for (int mi=0;mi<4;mi++) oacc[mi][ni] *= scl[ni];
      }
      #pragma unroll
      for (int t=0;t<2;t++)
        #pragma unroll
        for (int mi=0;mi<4;mi++){
          const short* vp = &Vs[mi*16+qi][cc*64 + t*32 + g*4];
          s16x4 lo = *(const s16x4*)vp;
          s16x4 hi = *(const s16x4*)(vp+16);
          s16x8 vf = {lo[0],lo[1],lo[2],lo[3],hi[0],hi[1],hi[2],hi[3]};
          #pragma unroll
          for (int ni=0;ni<2;ni++)
            oacc[mi][ni] = MFMA(vf, pf[t][ni], oacc[mi][ni]);
        }
    }
  }
  #pragma unroll
  for (int ni=0;ni<2;ni++){
    float inv = 1.f / lrun[ni];
    int qg = w*256 + wq0 + ni*16 + qi;
    #pragma unroll
    for (int mi=0;mi<4;mi++){
      s16x4 st;
      #pragma unroll
      for (int r=0;r<4;r++) st[r] = f2bf(oacc[mi][ni][r]*inv);
      *(s16x4*)(attn_o + (size_t)qg*512 + h*64 + mi*16 + g*4) = st;
    }
  }
}

extern "C" void kernel_launch(void* const* d_in, const int* in_sizes, int n_in,
                              void* d_out, int out_size, void* d_ws, size_t ws_size,
                              hipStream_t stream)
{
  const float* x_in = (const float*)d_in[0];
  const float* Wqkv = (const float*)d_in[1];
  const float* Wo   = (const float*)d_in[2];
  const float* qsc  = (const float*)d_in[3];
  const float* ksc  = (const float*)d_in[4];
  const float* W1   = (const float*)d_in[5];
  const float* b1   = (const float*)d_in[6];
  const float* W2   = (const float*)d_in[7];
  const float* b2   = (const float*)d_in[8];
  float* xf = (float*)d_out;

  char* ws = (char*)d_ws;
  size_t off = 0;
  float* tab  = (float*)(ws + off); off += (size_t)4*8192*64*4;
  short* WqkvT= (short*)(ws + off); off += (size_t)6*1536*512*2;
  short* WoT  = (short*)(ws + off); off += (size_t)6*512*512*2;
  short* W1T  = (short*)(ws + off); off += (size_t)6*2730*512*2;
  short* W2T  = (short*)(ws + off); off += (size_t)6*512*1536*2;   // K padded 1376->1536 (zeros)
  short* xbf  = (short*)(ws + off); off += (size_t)8192*512*2;
  short* qkv  = (short*)(ws + off); off += (size_t)8192*1536*2;
  short* qrot = (short*)(ws + off); off += (size_t)8*8192*64*2;
  short* krot = (short*)(ws + off); off += (size_t)8*8192*64*2;
  short* vt   = (short*)(ws + off); off += (size_t)8*8192*64*2;
  short* attno= (short*)(ws + off); off += (size_t)8192*512*2;
  short* hg   = (short*)(ws + off); off += (size_t)8192*1376*2 + 4096; // pad: W2 A-stream overreads <=320B

  hipMemcpyAsync(xf, x_in, (size_t)8192*512*4, hipMemcpyDeviceToDevice, stream);
  rope_k<<<8192, 64, 0, stream>>>(tab);
  wtrans_k<<<dim3(24,8,6),256,0,stream>>>(Wqkv, WqkvT, 512,1536,512, (long)512*1536, (long)1536*512);
  wtrans_k<<<dim3(8,8,6),256,0,stream>>>(Wo, WoT, 512,512,512, (long)512*512,(long)512*512);
  wtrans_k<<<dim3(43,8,6),256,0,stream>>>(W1, W1T, 512,2730,512, (long)512*2730,(long)2730*512);
  wtrans_k<<<dim3(8,24,6),256,0,stream>>>(W2, W2T, 1365,512,1536, (long)1365*512,(long)512*1536);
  cast_k<<<4096,256,0,stream>>>(x_in, xbf);

  for (int l=0;l<6;l++){
    // QKV: M=8192 N=1536 K=512  (tile 256x64)
    gemm_s<4,16,1, 0,0,0,1><<<dim3(32,24),256,0,stream>>>(xbf, WqkvT + (size_t)l*1536*512,
        nullptr, nullptr, nullptr, qkv, 1536, 512, 512);
    qkprep_k<<<16384,256,0,stream>>>(qkv, tab, qsc + l*64, ksc + l*64, qrot, krot);
    vtrans_k<<<dim3(128,8),256,0,stream>>>(qkv, vt);
    attn_k<<<dim3(32,8),512,0,stream>>>(qrot, krot, vt, attno);
    // Wo: M=8192 N=512 K=512  (tile 128x64)
    gemm_s<2,16,1, 0,1,1,1><<<dim3(64,8),256,0,stream>>>(attno, WoT + (size_t)l*512*512,
        nullptr, xf, xf, xbf, 512, 512, 512);
    // FF1+GEGLU: N=1365(->1408) K=512 (tile 256x64, dual panel)
    geglu_s<<<dim3(32,22),256,0,stream>>>(xbf, W1T + (size_t)l*2730*512, b1 + (size_t)l*2730, hg);
    // W2: M=8192 N=512 K=1376 (padded 1536, 3 chunks; A-overread x B-zeros = 0)
    gemm_s<2,16,3, 1,1,1,1><<<dim3(64,8),256,0,stream>>>(hg, W2T + (size_t)l*512*1536,
        b2 + (size_t)l*512, xf, xf, xbf, 512, 1376, 1536);
  }
}

// Round 7
// 1145.580 us; speedup vs baseline: 1.5066x; 1.5066x over previous
//
#include <hip/hip_runtime.h>
#include <hip/hip_bf16.h>
#include <math.h>

typedef short s16x8 __attribute__((ext_vector_type(8)));
typedef short s16x4 __attribute__((ext_vector_type(4)));
typedef float f32x4 __attribute__((ext_vector_type(4)));

#define MFMA(A,B,C) __builtin_amdgcn_mfma_f32_16x16x32_bf16((A),(B),(C),0,0,0)

typedef __attribute__((address_space(3))) unsigned int lds_u32;
typedef __attribute__((address_space(1))) const unsigned int glb_u32;
__device__ __forceinline__ void gload16(const short* g, const short* l){
  __builtin_amdgcn_global_load_lds((glb_u32*)g, (lds_u32*)l, 16, 0, 0);
}

__device__ __forceinline__ float bf2f(short u){
  unsigned int x = ((unsigned int)(unsigned short)u) << 16;
  return __builtin_bit_cast(float, x);
}
__device__ __forceinline__ short f2bf(float f){
  unsigned int x = __builtin_bit_cast(unsigned int, f);
  x += 0x7fffu + ((x >> 16) & 1u);
  return (short)(x >> 16);
}
// tanh-form gelu, overflow-safe
__device__ __forceinline__ float gelu_t(float x){
  float u = x + 0.044715f*x*x*x;
  float e = __expf(1.5957691216057308f*u);
  float th = 1.f - 2.f/(e + 1.f);
  return 0.5f*x*(1.f + th);
}

// bijective XCD-chunk swizzle (m204 formula)
__device__ __forceinline__ void xcd_swz(int gx, int gy, int &bx, int &by){
  int id = bx + by*gx;
  int nwg = gx*gy;
  int q = nwg >> 3, r = nwg & 7;
  int xcd = id & 7, idx = id >> 3;
  int nid = (xcd < r ? xcd*(q+1) : r*(q+1) + (xcd-r)*q) + idx;
  bx = nid % gx; by = nid / gx;
}

#define FFI 1365
#define FFIP 1376

// ---------------- GEMM 128x128, 512 thr, 8 waves, 2-phase dbuf (R4 structure) ----------------
template<int HAS_BIAS, int HAS_RES, int OUT_F32, int OUT_BF16>
__global__ __launch_bounds__(512) void gemm_k(
    const short* __restrict__ A, const short* __restrict__ Bt,
    const float* __restrict__ bias, const float* __restrict__ res,
    float* __restrict__ outF, short* __restrict__ outB,
    int M, int N, int K)
{
  __shared__ short As[2][128*32];
  __shared__ short Bs[2][128*32];
  const int tid = threadIdx.x;
  const int lane = tid & 63, wv = tid >> 6;
  const int g = lane >> 4, qi = lane & 15;
  int bx = blockIdx.x, by = blockIdx.y;
  xcd_swz(gridDim.x, gridDim.y, bx, by);
  const int m0 = bx * 128, n0 = by * 128;
  const int wm = (wv >> 2) * 64, wn = (wv & 3) * 32;

  const int sr = tid >> 2, sc = (tid & 3) * 8;
  const short* Ag = A  + (size_t)(m0 + sr)*K + sc;
  const short* Bg = Bt + (size_t)(n0 + sr)*K + sc;

  f32x4 acc[4][2];
  #pragma unroll
  for (int i=0;i<4;i++)
    #pragma unroll
    for (int j=0;j<2;j++) acc[i][j] = (f32x4){0.f,0.f,0.f,0.f};

  auto stage = [&](int buf, int k0){
    gload16(Ag + k0, &As[buf][wv*512]);
    gload16(Bg + k0, &Bs[buf][wv*512]);
  };

  const int nt = K >> 5;
  stage(0, 0);
  __syncthreads();
  for (int t = 0; t < nt; ++t) {
    const int cur = t & 1;
    if (t + 1 < nt) stage(cur ^ 1, (t+1) << 5);
    s16x8 af[4], bf[2];
    #pragma unroll
    for (int mi=0;mi<4;mi++) af[mi] = *(const s16x8*)&As[cur][(wm+mi*16+qi)*32 + g*8];
    #pragma unroll
    for (int ni=0;ni<2;ni++) bf[ni] = *(const s16x8*)&Bs[cur][(wn+ni*16+qi)*32 + g*8];
    #pragma unroll
    for (int mi=0;mi<4;mi++)
      #pragma unroll
      for (int ni=0;ni<2;ni++)
        acc[mi][ni] = MFMA(af[mi], bf[ni], acc[mi][ni]);
    __syncthreads();
  }
  #pragma unroll
  for (int mi=0;mi<4;mi++){
    #pragma unroll
    for (int r=0;r<4;r++){
      int row = m0 + wm + mi*16 + g*4 + r;
      #pragma unroll
      for (int ni=0;ni<2;ni++){
        int col = n0 + wn + ni*16 + qi;
        float v = acc[mi][ni][r];
        if (HAS_BIAS) v += bias[col];
        if (HAS_RES)  v += res[(size_t)row*N + col];
        if (OUT_F32)  outF[(size_t)row*N + col] = v;
        if (OUT_BF16) outB[(size_t)row*N + col] = f2bf(v);
      }
    }
  }
}

// ---------------- GEMM 64x64, 256 thr, 4 waves (for N=512 skinny gemms: more blocks/CU) ----------------
template<int HAS_BIAS, int HAS_RES, int OUT_F32, int OUT_BF16>
__global__ __launch_bounds__(256) void gemm64_k(
    const short* __restrict__ A, const short* __restrict__ Bt,
    const float* __restrict__ bias, const float* __restrict__ res,
    float* __restrict__ outF, short* __restrict__ outB,
    int M, int N, int K)
{
  __shared__ short As[2][64*32];
  __shared__ short Bs[2][64*32];
  const int tid = threadIdx.x;
  const int lane = tid & 63, wv = tid >> 6;
  const int g = lane >> 4, qi = lane & 15;
  int bx = blockIdx.x, by = blockIdx.y;
  xcd_swz(gridDim.x, gridDim.y, bx, by);
  const int m0 = bx * 64, n0 = by * 64;
  const int wm = (wv >> 1) * 32, wn = (wv & 1) * 32;

  const int sr = tid >> 2, sc = (tid & 3) * 8;
  const short* Ag = A  + (size_t)(m0 + sr)*K + sc;
  const short* Bg = Bt + (size_t)(n0 + sr)*K + sc;

  f32x4 acc[2][2];
  #pragma unroll
  for (int i=0;i<2;i++)
    #pragma unroll
    for (int j=0;j<2;j++) acc[i][j] = (f32x4){0.f,0.f,0.f,0.f};

  auto stage = [&](int buf, int k0){
    gload16(Ag + k0, &As[buf][wv*512]);
    gload16(Bg + k0, &Bs[buf][wv*512]);
  };

  const int nt = K >> 5;
  stage(0, 0);
  __syncthreads();
  for (int t = 0; t < nt; ++t) {
    const int cur = t & 1;
    if (t + 1 < nt) stage(cur ^ 1, (t+1) << 5);
    s16x8 af[2], bf[2];
    #pragma unroll
    for (int mi=0;mi<2;mi++) af[mi] = *(const s16x8*)&As[cur][(wm+mi*16+qi)*32 + g*8];
    #pragma unroll
    for (int ni=0;ni<2;ni++) bf[ni] = *(const s16x8*)&Bs[cur][(wn+ni*16+qi)*32 + g*8];
    #pragma unroll
    for (int mi=0;mi<2;mi++)
      #pragma unroll
      for (int ni=0;ni<2;ni++)
        acc[mi][ni] = MFMA(af[mi], bf[ni], acc[mi][ni]);
    __syncthreads();
  }
  #pragma unroll
  for (int mi=0;mi<2;mi++){
    #pragma unroll
    for (int r=0;r<4;r++){
      int row = m0 + wm + mi*16 + g*4 + r;
      #pragma unroll
      for (int ni=0;ni<2;ni++){
        int col = n0 + wn + ni*16 + qi;
        float v = acc[mi][ni][r];
        if (HAS_BIAS) v += bias[col];
        if (HAS_RES)  v += res[(size_t)row*N + col];
        if (OUT_F32)  outF[(size_t)row*N + col] = v;
        if (OUT_BF16) outB[(size_t)row*N + col] = f2bf(v);
      }
    }
  }
}

// ---------------- FF1 + GEGLU fused (R4 structure) ----------------
__global__ __launch_bounds__(512) void geglu_k(
    const short* __restrict__ A, const short* __restrict__ Bt,
    const float* __restrict__ b1, short* __restrict__ hg)
{
  __shared__ short As[2][128*32];
  __shared__ short Ba[2][128*32];
  __shared__ short Bg[2][128*32];
  const int tid = threadIdx.x;
  const int lane = tid & 63, wv = tid >> 6;
  const int g = lane >> 4, qi = lane & 15;
  int bx = blockIdx.x, by = blockIdx.y;
  xcd_swz(gridDim.x, gridDim.y, bx, by);
  const int m0 = bx * 128, n0 = by * 128;
  const int wm = (wv >> 2) * 64, wn = (wv & 3) * 32;

  const int sr = tid >> 2, sc = (tid & 3) * 8;
  const short* Ag = A + (size_t)(m0 + sr)*512 + sc;
  const short* Pa = Bt + (size_t)min(n0 + sr, FFI-1)*512 + sc;
  const short* Pg = Bt + (size_t)min(FFI + n0 + sr, 2729)*512 + sc;

  f32x4 aa[4][2], ag[4][2];
  #pragma unroll
  for (int i=0;i<4;i++)
    #pragma unroll
    for (int j=0;j<2;j++){ aa[i][j]=(f32x4){0.f,0.f,0.f,0.f}; ag[i][j]=(f32x4){0.f,0.f,0.f,0.f}; }

  auto stage = [&](int buf, int k0){
    gload16(Ag + k0, &As[buf][wv*512]);
    gload16(Pa + k0, &Ba[buf][wv*512]);
    gload16(Pg + k0, &Bg[buf][wv*512]);
  };

  stage(0, 0);
  __syncthreads();
  for (int t = 0; t < 16; ++t) {
    const int cur = t & 1;
    if (t + 1 < 16) stage(cur ^ 1, (t+1) << 5);
    s16x8 af[4], bfa[2], bfg[2];
    #pragma unroll
    for (int mi=0;mi<4;mi++) af[mi] = *(const s16x8*)&As[cur][(wm+mi*16+qi)*32 + g*8];
    #pragma unroll
    for (int ni=0;ni<2;ni++){ bfa[ni] = *(const s16x8*)&Ba[cur][(wn+ni*16+qi)*32 + g*8];
                              bfg[ni] = *(const s16x8*)&Bg[cur][(wn+ni*16+qi)*32 + g*8]; }
    #pragma unroll
    for (int mi=0;mi<4;mi++)
      #pragma unroll
      for (int ni=0;ni<2;ni++){
        aa[mi][ni] = MFMA(af[mi], bfa[ni], aa[mi][ni]);
        ag[mi][ni] = MFMA(af[mi], bfg[ni], ag[mi][ni]);
      }
    __syncthreads();
  }
  #pragma unroll
  for (int mi=0;mi<4;mi++){
    #pragma unroll
    for (int r=0;r<4;r++){
      int row = m0 + wm + mi*16 + g*4 + r;
      #pragma unroll
      for (int ni=0;ni<2;ni++){
        int col = n0 + wn + ni*16 + qi;
        if (col < FFI){
          float va = aa[mi][ni][r] + b1[col];
          float vg = ag[mi][ni][r] + b1[FFI+col];
          hg[(size_t)row*FFIP + col] = f2bf(va * gelu_t(vg));
        } else if (col < FFIP){
          hg[(size_t)row*FFIP + col] = 0;
        }
      }
    }
  }
}

// ---------------- rotary/xpos tables (f64 precompute) ----------------
__global__ void rope_k(float* __restrict__ tab){
  int n = blockIdx.x, dd = threadIdx.x;
  int i = dd & 31;
  double invf = pow(10000.0, -(double)i/32.0);
  double fr = (double)n * invf;
  double c = cos(fr), s = sin(fr);
  double sv = (2.0*i + 25.6)/89.6;
  double pw = ((double)n - 4096.0)/128.0;
  double xs = pow(sv, pw);
  size_t o = (size_t)n*64 + dd;
  tab[o]            = (float)(c*xs);
  tab[524288+o]     = (float)(s*xs);
  tab[2*524288+o]   = (float)(c/xs);
  tab[3*524288+o]   = (float)(s/xs);
}

// ---------------- weight transpose+cast ----------------
__global__ __launch_bounds__(256) void wtrans_k(
    const float* __restrict__ src, short* __restrict__ dst,
    int K, int N, int Kp, long srcStride, long dstStride)
{
  __shared__ float t[64][65];
  const float* s = src + (size_t)blockIdx.z * srcStride;
  short* d = dst + (size_t)blockIdx.z * dstStride;
  int n0 = blockIdx.x*64, k0 = blockIdx.y*64;
  int tid = threadIdx.x;
  #pragma unroll
  for (int p=0;p<4;p++){
    int task = p*256+tid;
    int r = task>>4, c = (task&15)*4;
    int k = k0 + r;
    #pragma unroll
    for (int e=0;e<4;e++){
      int n = n0+c+e;
      t[r][c+e] = (k<K && n<N) ? s[(size_t)k*N+n] : 0.f;
    }
  }
  __syncthreads();
  #pragma unroll
  for (int p=0;p<2;p++){
    int task = p*256+tid;
    int nr = task>>3, kg=(task&7)*8;
    int n = n0+nr;
    if (n < N && (k0+kg) < Kp){
      s16x8 v;
      #pragma unroll
      for (int j=0;j<8;j++) v[j] = f2bf(t[kg+j][nr]);
      *(s16x8*)(d + (size_t)n*Kp + k0 + kg) = v;
    }
  }
}

// ---------------- f32 -> bf16 cast ----------------
__global__ void cast_k(const float* __restrict__ in, short* __restrict__ out){
  int i = (blockIdx.x*256+threadIdx.x)*4;
  float4 v = *(const float4*)(in+i);
  s16x4 o = { f2bf(v.x), f2bf(v.y), f2bf(v.z), f2bf(v.w) };
  *(s16x4*)(out+i) = o;
}

// ---------------- q/k: l2norm + scale + xpos rotary (2048 blocks, 8-iter loop) ----------------
__global__ __launch_bounds__(256) void qkprep_k(
    const short* __restrict__ qkv, const float* __restrict__ tab,
    const float* __restrict__ qs, const float* __restrict__ ks,
    short* __restrict__ qrot, short* __restrict__ krot)
{
  int wv = threadIdx.x >> 6, lane = threadIdx.x & 63;
  float qsc = qs[lane], ksc = ks[lane];
  #pragma unroll
  for (int it=0; it<8; ++it){
    int wid = it*8192 + blockIdx.x*4 + wv;
    int n = wid >> 3, h = wid & 7;
    float qv = bf2f(qkv[(size_t)n*1536 + h*64 + lane]);
    float kv = bf2f(qkv[(size_t)n*1536 + 512 + h*64 + lane]);
    float sq = qv*qv, sk = kv*kv;
    #pragma unroll
    for (int m=1;m<64;m<<=1){ sq += __shfl_xor(sq,m,64); sk += __shfl_xor(sk,m,64); }
    qv *= qsc / fmaxf(sqrtf(sq), 1e-12f);
    kv *= ksc / fmaxf(sqrtf(sk), 1e-12f);
    float qo = __shfl_xor(qv,32,64), ko = __shfl_xor(kv,32,64);
    float sgn = (lane<32)? -1.f : 1.f;
    size_t to = (size_t)n*64 + lane;
    float cq = tab[to], sxq = tab[524288+to], ck = tab[2*524288+to], sxk = tab[3*524288+to];
    qrot[((size_t)h*8192+n)*64+lane] = f2bf(qv*cq + sgn*qo*sxq);
    krot[((size_t)h*8192+n)*64+lane] = f2bf(kv*ck + sgn*ko*sxk);
  }
}

// ---------------- V transpose: vt[h][d][n] ----------------
__global__ __launch_bounds__(256) void vtrans_k(const short* __restrict__ qkv, short* __restrict__ vt){
  __shared__ short t[64][72];
  int n0 = blockIdx.x*64, h = blockIdx.y;
  int tid = threadIdx.x;
  #pragma unroll
  for (int p=0;p<2;p++){
    int task = p*256+tid;
    int r = task>>3, cg = (task&7)*8;
    *(s16x8*)&t[r][cg] = *(const s16x8*)(qkv + (size_t)(n0+r)*1536 + 1024 + h*64 + cg);
  }
  __syncthreads();
  #pragma unroll
  for (int p=0;p<2;p++){
    int task = p*256+tid;
    int d = task>>3, nb = (task&7)*8;
    s16x8 v;
    #pragma unroll
    for (int j=0;j<8;j++) v[j] = t[nb+j][d];
    *(s16x8*)(vt + ((size_t)h*64+d)*8192 + n0 + nb) = v;
  }
}

// ---------------- local windowed attention: half-window blocks, 8 waves x 16 q-rows ----------------
__global__ __launch_bounds__(512,1) void attn_k(
    const short* __restrict__ qrot, const short* __restrict__ krot,
    const short* __restrict__ vt, short* __restrict__ attn_o)
{
  __shared__ short Ks[128][72];
  __shared__ short Vs[64][136];
  const int bxx = blockIdx.x, h = blockIdx.y;
  const int w = bxx >> 1, half = bxx & 1;
  const int tid = threadIdx.x, lane = tid & 63, wv = tid >> 6;
  const int g = lane >> 4, qi = lane & 15;
  const int wq = half*128 + wv*16;          // window-local q base for this wave
  const int q0abs = w*256 + wq;
  s16x8 qf[2];
  {
    const short* p = qrot + ((size_t)h*8192 + q0abs + qi)*64 + g*8;
    qf[0] = *(const s16x8*)p;
    qf[1] = *(const s16x8*)(p + 32);
  }
  f32x4 oacc[4];
  #pragma unroll
  for (int j=0;j<4;j++) oacc[j]=(f32x4){0.f,0.f,0.f,0.f};
  float mrun = -1e30f, lrun = 0.f;
  const int kvbase = w*256 - 256;
  for (int s=half; s<half+3; ++s){
    __syncthreads();
    #pragma unroll
    for (int p=0;p<2;p++){
      int task = p*512 + tid;
      {
        int r = task>>3, cg = (task&7)*8;
        int jg = kvbase + s*128 + r;
        s16x8 v = {0,0,0,0,0,0,0,0};
        if (jg>=0) v = *(const s16x8*)(krot + ((size_t)h*8192+jg)*64 + cg);
        *(s16x8*)&Ks[r][cg] = v;
      }
      {
        int dd = task>>4, cg = (task&15)*8;
        int jg = kvbase + s*128 + cg;
        s16x8 v = {0,0,0,0,0,0,0,0};
        if (jg>=0) v = *(const s16x8*)(vt + ((size_t)h*64+dd)*8192 + jg);
        *(s16x8*)&Vs[dd][cg] = v;
      }
    }
    __syncthreads();
    for (int cc=0;cc<2;cc++){
      const int jlo = s*128 + cc*64;          // window-local j base of this 64-block
      if (jlo + 63 < wq) continue;            // all keys "future-masked" side
      if (jlo > wq + 271) continue;           // beyond max ql+256
      if (w==0 && jlo < 256) continue;        // j_abs < 0 zero-pad region
      f32x4 sacc[4];
      #pragma unroll
      for (int i=0;i<4;i++) sacc[i]=(f32x4){0.f,0.f,0.f,0.f};
      #pragma unroll
      for (int ks=0;ks<2;ks++){
        s16x8 kf[4];
        #pragma unroll
        for (int mi=0;mi<4;mi++) kf[mi] = *(const s16x8*)&Ks[cc*64+mi*16+qi][ks*32+g*8];
        #pragma unroll
        for (int mi=0;mi<4;mi++)
          sacc[mi] = MFMA(kf[mi], qf[ks], sacc[mi]);
      }
      const bool interior = (jlo >= wq+15) && (jlo+63 <= wq+256);
      float cmax = -1e30f;
      #pragma unroll
      for (int mi=0;mi<4;mi++)
        #pragma unroll
        for (int r=0;r<4;r++){
          float x = sacc[mi][r] * 8.f;
          if (!interior){
            int j = jlo + mi*16 + g*4 + r;
            int ql = wq + qi;
            if (j < ql || j > ql+256) x = -1e30f;
          }
          sacc[mi][r] = x;
          cmax = fmaxf(cmax, x);
        }
      cmax = fmaxf(cmax, __shfl_xor(cmax,16,64));
      cmax = fmaxf(cmax, __shfl_xor(cmax,32,64));
      float mn = fmaxf(mrun, cmax);
      float scl = __expf(mrun - mn);
      mrun = mn;
      float ps = 0.f;
      s16x8 pf[2];
      #pragma unroll
      for (int t=0;t<2;t++)
        #pragma unroll
        for (int hh=0; hh<2; hh++){
          int mi = 2*t+hh;
          #pragma unroll
          for (int r=0;r<4;r++){
            float pv = __expf(sacc[mi][r]-mn);
            ps += pv;
            pf[t][hh*4+r] = f2bf(pv);
          }
        }
      ps += __shfl_xor(ps,16,64);
      ps += __shfl_xor(ps,32,64);
      lrun = lrun*scl + ps;
      #pragma unroll
      for (int mi=0;mi<4;mi++) oacc[mi] *= scl;
      #pragma unroll
      for (int t=0;t<2;t++)
        #pragma unroll
        for (int mi=0;mi<4;mi++){
          const short* vp = &Vs[mi*16+qi][cc*64 + t*32 + g*4];
          s16x4 lo = *(const s16x4*)vp;
          s16x4 hi = *(const s16x4*)(vp+16);
          s16x8 vf = {lo[0],lo[1],lo[2],lo[3],hi[0],hi[1],hi[2],hi[3]};
          oacc[mi] = MFMA(vf, pf[t], oacc[mi]);
        }
    }
  }
  float inv = 1.f / lrun;
  #pragma unroll
  for (int mi=0;mi<4;mi++){
    s16x4 st;
    #pragma unroll
    for (int r=0;r<4;r++) st[r] = f2bf(oacc[mi][r]*inv);
    *(s16x4*)(attn_o + (size_t)(q0abs+qi)*512 + h*64 + mi*16 + g*4) = st;
  }
}

extern "C" void kernel_launch(void* const* d_in, const int* in_sizes, int n_in,
                              void* d_out, int out_size, void* d_ws, size_t ws_size,
                              hipStream_t stream)
{
  const float* x_in = (const float*)d_in[0];
  const float* Wqkv = (const float*)d_in[1];
  const float* Wo   = (const float*)d_in[2];
  const float* qsc  = (const float*)d_in[3];
  const float* ksc  = (const float*)d_in[4];
  const float* W1   = (const float*)d_in[5];
  const float* b1   = (const float*)d_in[6];
  const float* W2   = (const float*)d_in[7];
  const float* b2   = (const float*)d_in[8];
  float* xf = (float*)d_out;

  char* ws = (char*)d_ws;
  size_t off = 0;
  float* tab  = (float*)(ws + off); off += (size_t)4*8192*64*4;
  short* WqkvT= (short*)(ws + off); off += (size_t)6*1536*512*2;
  short* WoT  = (short*)(ws + off); off += (size_t)6*512*512*2;
  short* W1T  = (short*)(ws + off); off += (size_t)6*2730*512*2;
  short* W2T  = (short*)(ws + off); off += (size_t)6*512*1376*2;
  short* xbf  = (short*)(ws + off); off += (size_t)8192*512*2;
  short* qkv  = (short*)(ws + off); off += (size_t)8192*1536*2;
  short* qrot = (short*)(ws + off); off += (size_t)8*8192*64*2;
  short* krot = (short*)(ws + off); off += (size_t)8*8192*64*2;
  short* vt   = (short*)(ws + off); off += (size_t)8*8192*64*2;
  short* attno= (short*)(ws + off); off += (size_t)8192*512*2;
  short* hg   = (short*)(ws + off); off += (size_t)8192*1376*2;

  hipMemcpyAsync(xf, x_in, (size_t)8192*512*4, hipMemcpyDeviceToDevice, stream);
  rope_k<<<8192, 64, 0, stream>>>(tab);
  wtrans_k<<<dim3(24,8,6),256,0,stream>>>(Wqkv, WqkvT, 512,1536,512, (long)512*1536, (long)1536*512);
  wtrans_k<<<dim3(8,8,6),256,0,stream>>>(Wo, WoT, 512,512,512, (long)512*512,(long)512*512);
  wtrans_k<<<dim3(43,8,6),256,0,stream>>>(W1, W1T, 512,2730,512, (long)512*2730,(long)2730*512);
  wtrans_k<<<dim3(8,22,6),256,0,stream>>>(W2, W2T, 1365,512,1376, (long)1365*512,(long)512*1376);
  cast_k<<<4096,256,0,stream>>>(x_in, xbf);

  for (int l=0;l<6;l++){
    gemm_k<0,0,0,1><<<dim3(64,12),512,0,stream>>>(xbf, WqkvT + (size_t)l*1536*512,
        nullptr, nullptr, nullptr, qkv, 8192,1536,512);
    qkprep_k<<<2048,256,0,stream>>>(qkv, tab, qsc + l*64, ksc + l*64, qrot, krot);
    vtrans_k<<<dim3(128,8),256,0,stream>>>(qkv, vt);
    attn_k<<<dim3(64,8),512,0,stream>>>(qrot, krot, vt, attno);
    gemm64_k<0,1,1,1><<<dim3(128,8),256,0,stream>>>(attno, WoT + (size_t)l*512*512,
        nullptr, xf, xf, xbf, 8192,512,512);
    geglu_k<<<dim3(64,11),512,0,stream>>>(xbf, W1T + (size_t)l*2730*512, b1 + (size_t)l*2730, hg);
    gemm64_k<1,1,1,1><<<dim3(128,8),256,0,stream>>>(hg, W2T + (size_t)l*512*1376,
        b2 + (size_t)l*512, xf, xf, xbf, 8192,512,1376);
  }
}

// Round 8
// 1099.058 us; speedup vs baseline: 1.5703x; 1.0423x over previous
//
#include <hip/hip_runtime.h>
#include <hip/hip_bf16.h>
#include <math.h>

typedef short s16x8 __attribute__((ext_vector_type(8)));
typedef short s16x4 __attribute__((ext_vector_type(4)));
typedef float f32x4 __attribute__((ext_vector_type(4)));

#define MFMA(A,B,C) __builtin_amdgcn_mfma_f32_16x16x32_bf16((A),(B),(C),0,0,0)

typedef __attribute__((address_space(3))) unsigned int lds_u32;
typedef __attribute__((address_space(1))) const unsigned int glb_u32;
__device__ __forceinline__ void gload16(const short* g, const short* l){
  __builtin_amdgcn_global_load_lds((glb_u32*)g, (lds_u32*)l, 16, 0, 0);
}

__device__ __forceinline__ float bf2f(short u){
  unsigned int x = ((unsigned int)(unsigned short)u) << 16;
  return __builtin_bit_cast(float, x);
}
__device__ __forceinline__ short f2bf(float f){
  unsigned int x = __builtin_bit_cast(unsigned int, f);
  x += 0x7fffu + ((x >> 16) & 1u);
  return (short)(x >> 16);
}
// tanh-form gelu, overflow-safe
__device__ __forceinline__ float gelu_t(float x){
  float u = x + 0.044715f*x*x*x;
  float e = __expf(1.5957691216057308f*u);
  float th = 1.f - 2.f/(e + 1.f);
  return 0.5f*x*(1.f + th);
}

// bijective XCD-chunk swizzle (m204 formula)
__device__ __forceinline__ void xcd_swz(int gx, int gy, int &bx, int &by){
  int id = bx + by*gx;
  int nwg = gx*gy;
  int q = nwg >> 3, r = nwg & 7;
  int xcd = id & 7, idx = id >> 3;
  int nid = (xcd < r ? xcd*(q+1) : r*(q+1) + (xcd-r)*q) + idx;
  bx = nid % gx; by = nid / gx;
}

#define FFI 1365
#define FFIP 1376

// ---------------- QKV GEMM + fused qk-prep (l2norm+scale+xpos rotary) + V transpose ----------------
// tile 128x128, 512 thr, 8 waves; by 0-3: q->qrot, 4-7: k->krot, 8-11: v->vt
__global__ __launch_bounds__(512) void qkv_fused_k(
    const short* __restrict__ A, const short* __restrict__ Bt,
    const float* __restrict__ tab,
    const float* __restrict__ qs, const float* __restrict__ ksc_,
    short* __restrict__ qrot, short* __restrict__ krot, short* __restrict__ vt)
{
  __shared__ short SBUF[16896];          // main loop: As(2x8KB)+Bs(2x8KB)=32KB; epilogue: [128][132] bf16
  __shared__ float ss[2][128][2];
  const int tid = threadIdx.x;
  const int lane = tid & 63, wv = tid >> 6;
  const int g = lane >> 4, qi = lane & 15;
  int bx = blockIdx.x, by = blockIdx.y;
  xcd_swz(gridDim.x, gridDim.y, bx, by);
  const int m0 = bx * 128, n0 = by * 128;
  const int wm = (wv >> 2) * 64, wn = (wv & 3) * 32;

  const int sr = tid >> 2, sc = (tid & 3) * 8;
  const short* Ag = A  + (size_t)(m0 + sr)*512 + sc;
  const short* Bg = Bt + (size_t)(n0 + sr)*512 + sc;

  f32x4 acc[4][2];
  #pragma unroll
  for (int i=0;i<4;i++)
    #pragma unroll
    for (int j=0;j<2;j++) acc[i][j] = (f32x4){0.f,0.f,0.f,0.f};

  auto stage = [&](int buf, int k0){
    gload16(Ag + k0, SBUF + buf*4096 + wv*512);
    gload16(Bg + k0, SBUF + 8192 + buf*4096 + wv*512);
  };

  stage(0, 0);
  __syncthreads();
  for (int t = 0; t < 16; ++t) {
    const int cur = t & 1;
    if (t + 1 < 16) stage(cur ^ 1, (t+1) << 5);
    s16x8 af[4], bf[2];
    #pragma unroll
    for (int mi=0;mi<4;mi++) af[mi] = *(const s16x8*)&SBUF[cur*4096 + (wm+mi*16+qi)*32 + g*8];
    #pragma unroll
    for (int ni=0;ni<2;ni++) bf[ni] = *(const s16x8*)&SBUF[8192 + cur*4096 + (wn+ni*16+qi)*32 + g*8];
    #pragma unroll
    for (int mi=0;mi<4;mi++)
      #pragma unroll
      for (int ni=0;ni<2;ni++)
        acc[mi][ni] = MFMA(af[mi], bf[ni], acc[mi][ni]);
    __syncthreads();
  }
  // ---- fused epilogue ----
  const int hl = (wv & 3) >> 1;        // head-local within the 128-col tile
  if (by < 8) {
    const bool isq = (by < 4);
    const int head = (isq ? by : (by-4))*2 + hl;
    const float* scale = isq ? qs : ksc_;
    // per-(row) sumsq over the 64-dim head: in-wave 32 cols, cross-wave combine
    #pragma unroll
    for (int mi=0;mi<4;mi++)
      #pragma unroll
      for (int r=0;r<4;r++){
        float s = acc[mi][0][r]*acc[mi][0][r] + acc[mi][1][r]*acc[mi][1][r];
        s += __shfl_xor(s,1,64); s += __shfl_xor(s,2,64);
        s += __shfl_xor(s,4,64); s += __shfl_xor(s,8,64);
        if (qi == 0) ss[wv & 1][wm + mi*16 + g*4 + r][hl] = s;
      }
    float sc0 = scale[(wn + qi) & 63], sc1 = scale[(wn + 16 + qi) & 63];
    __syncthreads();
    float nva[4][2][4];
    #pragma unroll
    for (int mi=0;mi<4;mi++)
      #pragma unroll
      for (int r=0;r<4;r++){
        int rowl = wm + mi*16 + g*4 + r;
        float stot = ss[0][rowl][hl] + ss[1][rowl][hl];
        float inv = 1.f / fmaxf(sqrtf(stot), 1e-12f);
        #pragma unroll
        for (int ni=0;ni<2;ni++){
          float nv = acc[mi][ni][r] * (ni ? sc1 : sc0) * inv;
          nva[mi][ni][r] = nv;
          int col = wn + ni*16 + qi;
          SBUF[rowl*132 + col] = f2bf(nv);
        }
      }
    __syncthreads();
    short* outp = isq ? qrot : krot;
    const float* tc = tab + (isq ? 0 : 2*524288);
    const float* ts = tab + (isq ? 524288 : 3*524288);
    #pragma unroll
    for (int mi=0;mi<4;mi++)
      #pragma unroll
      for (int r=0;r<4;r++){
        int rowl = wm + mi*16 + g*4 + r;
        int n = m0 + rowl;
        #pragma unroll
        for (int ni=0;ni<2;ni++){
          int col = wn + ni*16 + qi;
          int d = col & 63;
          float partner = bf2f(SBUF[rowl*132 + (col ^ 32)]);
          float sgn = (d < 32) ? -1.f : 1.f;
          size_t to = (size_t)n*64 + d;
          float out = nva[mi][ni][r]*tc[to] + sgn*partner*ts[to];
          outp[((size_t)head*8192 + n)*64 + d] = f2bf(out);
        }
      }
  } else {
    // v: transpose through LDS to vt[h][d][n]
    const int hbase = (by - 8) * 2;
    #pragma unroll
    for (int mi=0;mi<4;mi++)
      #pragma unroll
      for (int r=0;r<4;r++){
        int rowl = wm + mi*16 + g*4 + r;
        #pragma unroll
        for (int ni=0;ni<2;ni++){
          int col = wn + ni*16 + qi;
          SBUF[rowl*132 + col] = f2bf(acc[mi][ni][r]);
        }
      }
    __syncthreads();
    #pragma unroll
    for (int p=0;p<4;p++){
      int task = p*512 + tid;
      int hl2 = task >> 10;
      int d = (task >> 4) & 63;
      int nb = (task & 15) * 8;
      int col = hl2*64 + d;
      s16x8 v;
      #pragma unroll
      for (int j=0;j<8;j++) v[j] = SBUF[(nb+j)*132 + col];
      *(s16x8*)(vt + ((size_t)(hbase+hl2)*64 + d)*8192 + m0 + nb) = v;
    }
  }
}

// ---------------- GEMM 128x64, 256 thr, 4 waves (N=512 skinny gemms) ----------------
template<int HAS_BIAS, int HAS_RES, int OUT_F32, int OUT_BF16>
__global__ __launch_bounds__(256) void gemm128x64_k(
    const short* __restrict__ A, const short* __restrict__ Bt,
    const float* __restrict__ bias, const float* __restrict__ res,
    float* __restrict__ outF, short* __restrict__ outB,
    int M, int N, int K)
{
  __shared__ short As[2][128*32];
  __shared__ short Bs[2][64*32];
  const int tid = threadIdx.x;
  const int lane = tid & 63, wv = tid >> 6;
  const int g = lane >> 4, qi = lane & 15;
  int bx = blockIdx.x, by = blockIdx.y;
  xcd_swz(gridDim.x, gridDim.y, bx, by);
  const int m0 = bx * 128, n0 = by * 64;
  const int wm = (wv >> 1) * 64, wn = (wv & 1) * 32;

  const int sr = wv*16 + (lane >> 2), sc = (lane & 3) * 8;
  const short* Ag = A  + (size_t)(m0 + sr)*K + sc;
  const short* Bg = Bt + (size_t)(n0 + sr)*K + sc;

  f32x4 acc[4][2];
  #pragma unroll
  for (int i=0;i<4;i++)
    #pragma unroll
    for (int j=0;j<2;j++) acc[i][j] = (f32x4){0.f,0.f,0.f,0.f};

  auto stage = [&](int buf, int k0){
    gload16(Ag + k0, &As[buf][wv*512]);
    gload16(Ag + (size_t)64*K + k0, &As[buf][2048 + wv*512]);
    gload16(Bg + k0, &Bs[buf][wv*512]);
  };

  const int nt = K >> 5;
  stage(0, 0);
  __syncthreads();
  for (int t = 0; t < nt; ++t) {
    const int cur = t & 1;
    if (t + 1 < nt) stage(cur ^ 1, (t+1) << 5);
    s16x8 af[4], bf[2];
    #pragma unroll
    for (int mi=0;mi<4;mi++) af[mi] = *(const s16x8*)&As[cur][(wm+mi*16+qi)*32 + g*8];
    #pragma unroll
    for (int ni=0;ni<2;ni++) bf[ni] = *(const s16x8*)&Bs[cur][(wn+ni*16+qi)*32 + g*8];
    #pragma unroll
    for (int mi=0;mi<4;mi++)
      #pragma unroll
      for (int ni=0;ni<2;ni++)
        acc[mi][ni] = MFMA(af[mi], bf[ni], acc[mi][ni]);
    __syncthreads();
  }
  #pragma unroll
  for (int mi=0;mi<4;mi++){
    #pragma unroll
    for (int r=0;r<4;r++){
      int row = m0 + wm + mi*16 + g*4 + r;
      #pragma unroll
      for (int ni=0;ni<2;ni++){
        int col = n0 + wn + ni*16 + qi;
        float v = acc[mi][ni][r];
        if (HAS_BIAS) v += bias[col];
        if (HAS_RES)  v += res[(size_t)row*N + col];
        if (OUT_F32)  outF[(size_t)row*N + col] = v;
        if (OUT_BF16) outB[(size_t)row*N + col] = f2bf(v);
      }
    }
  }
}

// ---------------- FF1 + GEGLU fused (R4 structure) ----------------
__global__ __launch_bounds__(512) void geglu_k(
    const short* __restrict__ A, const short* __restrict__ Bt,
    const float* __restrict__ b1, short* __restrict__ hg)
{
  __shared__ short As[2][128*32];
  __shared__ short Ba[2][128*32];
  __shared__ short Bg[2][128*32];
  const int tid = threadIdx.x;
  const int lane = tid & 63, wv = tid >> 6;
  const int g = lane >> 4, qi = lane & 15;
  int bx = blockIdx.x, by = blockIdx.y;
  xcd_swz(gridDim.x, gridDim.y, bx, by);
  const int m0 = bx * 128, n0 = by * 128;
  const int wm = (wv >> 2) * 64, wn = (wv & 3) * 32;

  const int sr = tid >> 2, sc = (tid & 3) * 8;
  const short* Ag = A + (size_t)(m0 + sr)*512 + sc;
  const short* Pa = Bt + (size_t)min(n0 + sr, FFI-1)*512 + sc;
  const short* Pg = Bt + (size_t)min(FFI + n0 + sr, 2729)*512 + sc;

  f32x4 aa[4][2], ag[4][2];
  #pragma unroll
  for (int i=0;i<4;i++)
    #pragma unroll
    for (int j=0;j<2;j++){ aa[i][j]=(f32x4){0.f,0.f,0.f,0.f}; ag[i][j]=(f32x4){0.f,0.f,0.f,0.f}; }

  auto stage = [&](int buf, int k0){
    gload16(Ag + k0, &As[buf][wv*512]);
    gload16(Pa + k0, &Ba[buf][wv*512]);
    gload16(Pg + k0, &Bg[buf][wv*512]);
  };

  stage(0, 0);
  __syncthreads();
  for (int t = 0; t < 16; ++t) {
    const int cur = t & 1;
    if (t + 1 < 16) stage(cur ^ 1, (t+1) << 5);
    s16x8 af[4], bfa[2], bfg[2];
    #pragma unroll
    for (int mi=0;mi<4;mi++) af[mi] = *(const s16x8*)&As[cur][(wm+mi*16+qi)*32 + g*8];
    #pragma unroll
    for (int ni=0;ni<2;ni++){ bfa[ni] = *(const s16x8*)&Ba[cur][(wn+ni*16+qi)*32 + g*8];
                              bfg[ni] = *(const s16x8*)&Bg[cur][(wn+ni*16+qi)*32 + g*8]; }
    #pragma unroll
    for (int mi=0;mi<4;mi++)
      #pragma unroll
      for (int ni=0;ni<2;ni++){
        aa[mi][ni] = MFMA(af[mi], bfa[ni], aa[mi][ni]);
        ag[mi][ni] = MFMA(af[mi], bfg[ni], ag[mi][ni]);
      }
    __syncthreads();
  }
  #pragma unroll
  for (int mi=0;mi<4;mi++){
    #pragma unroll
    for (int r=0;r<4;r++){
      int row = m0 + wm + mi*16 + g*4 + r;
      #pragma unroll
      for (int ni=0;ni<2;ni++){
        int col = n0 + wn + ni*16 + qi;
        if (col < FFI){
          float va = aa[mi][ni][r] + b1[col];
          float vg = ag[mi][ni][r] + b1[FFI+col];
          hg[(size_t)row*FFIP + col] = f2bf(va * gelu_t(vg));
        } else if (col < FFIP){
          hg[(size_t)row*FFIP + col] = 0;
        }
      }
    }
  }
}

// ---------------- rotary/xpos tables (f32 fast) ----------------
__global__ void rope_k(float* __restrict__ tab){
  int n = blockIdx.x, dd = threadIdx.x;
  int i = dd & 31;
  float invf = exp2f(-(float)i * (13.287712379549449f/32.0f));  // 10000^(-i/32)
  float fr = (float)n * invf;
  float c = cosf(fr), s = sinf(fr);
  float sv = (2.0f*i + 25.6f)/89.6f;
  float pw = ((float)n - 4096.0f)/128.0f;
  float xs = exp2f(pw * log2f(sv));
  size_t o = (size_t)n*64 + dd;
  tab[o]            = c*xs;
  tab[524288+o]     = s*xs;
  tab[2*524288+o]   = c/xs;
  tab[3*524288+o]   = s/xs;
}

// ---------------- weight transpose+cast ----------------
__global__ __launch_bounds__(256) void wtrans_k(
    const float* __restrict__ src, short* __restrict__ dst,
    int K, int N, int Kp, long srcStride, long dstStride)
{
  __shared__ float t[64][65];
  const float* s = src + (size_t)blockIdx.z * srcStride;
  short* d = dst + (size_t)blockIdx.z * dstStride;
  int n0 = blockIdx.x*64, k0 = blockIdx.y*64;
  int tid = threadIdx.x;
  #pragma unroll
  for (int p=0;p<4;p++){
    int task = p*256+tid;
    int r = task>>4, c = (task&15)*4;
    int k = k0 + r;
    #pragma unroll
    for (int e=0;e<4;e++){
      int n = n0+c+e;
      t[r][c+e] = (k<K && n<N) ? s[(size_t)k*N+n] : 0.f;
    }
  }
  __syncthreads();
  #pragma unroll
  for (int p=0;p<2;p++){
    int task = p*256+tid;
    int nr = task>>3, kg=(task&7)*8;
    int n = n0+nr;
    if (n < N && (k0+kg) < Kp){
      s16x8 v;
      #pragma unroll
      for (int j=0;j<8;j++) v[j] = f2bf(t[kg+j][nr]);
      *(s16x8*)(d + (size_t)n*Kp + k0 + kg) = v;
    }
  }
}

// ---------------- f32 -> bf16 cast ----------------
__global__ void cast_k(const float* __restrict__ in, short* __restrict__ out){
  int i = (blockIdx.x*256+threadIdx.x)*4;
  float4 v = *(const float4*)(in+i);
  s16x4 o = { f2bf(v.x), f2bf(v.y), f2bf(v.z), f2bf(v.w) };
  *(s16x4*)(out+i) = o;
}

// ---------------- local windowed attention: half-window blocks, 8 waves x 16 q-rows ----------------
__global__ __launch_bounds__(512,1) void attn_k(
    const short* __restrict__ qrot, const short* __restrict__ krot,
    const short* __restrict__ vt, short* __restrict__ attn_o)
{
  __shared__ short Ks[128][72];
  __shared__ short Vs[64][136];
  const int bxx = blockIdx.x, h = blockIdx.y;
  const int w = bxx >> 1, half = bxx & 1;
  const int tid = threadIdx.x, lane = tid & 63, wv = tid >> 6;
  const int g = lane >> 4, qi = lane & 15;
  const int wq = half*128 + wv*16;
  const int q0abs = w*256 + wq;
  s16x8 qf[2];
  {
    const short* p = qrot + ((size_t)h*8192 + q0abs + qi)*64 + g*8;
    qf[0] = *(const s16x8*)p;
    qf[1] = *(const s16x8*)(p + 32);
  }
  f32x4 oacc[4];
  #pragma unroll
  for (int j=0;j<4;j++) oacc[j]=(f32x4){0.f,0.f,0.f,0.f};
  float mrun = -1e30f, lrun = 0.f;
  const int kvbase = w*256 - 256;
  for (int s=half; s<half+3; ++s){
    __syncthreads();
    #pragma unroll
    for (int p=0;p<2;p++){
      int task = p*512 + tid;
      {
        int r = task>>3, cg = (task&7)*8;
        int jg = kvbase + s*128 + r;
        s16x8 v = {0,0,0,0,0,0,0,0};
        if (jg>=0) v = *(const s16x8*)(krot + ((size_t)h*8192+jg)*64 + cg);
        *(s16x8*)&Ks[r][cg] = v;
      }
      {
        int dd = task>>4, cg = (task&15)*8;
        int jg = kvbase + s*128 + cg;
        s16x8 v = {0,0,0,0,0,0,0,0};
        if (jg>=0) v = *(const s16x8*)(vt + ((size_t)h*64+dd)*8192 + jg);
        *(s16x8*)&Vs[dd][cg] = v;
      }
    }
    __syncthreads();
    for (int cc=0;cc<2;cc++){
      const int jlo = s*128 + cc*64;
      if (jlo + 63 < wq) continue;
      if (jlo > wq + 271) continue;
      if (w==0 && jlo < 256) continue;
      f32x4 sacc[4];
      #pragma unroll
      for (int i=0;i<4;i++) sacc[i]=(f32x4){0.f,0.f,0.f,0.f};
      #pragma unroll
      for (int ks=0;ks<2;ks++){
        s16x8 kf[4];
        #pragma unroll
        for (int mi=0;mi<4;mi++) kf[mi] = *(const s16x8*)&Ks[cc*64+mi*16+qi][ks*32+g*8];
        #pragma unroll
        for (int mi=0;mi<4;mi++)
          sacc[mi] = MFMA(kf[mi], qf[ks], sacc[mi]);
      }
      const bool interior = (jlo >= wq+15) && (jlo+63 <= wq+256);
      float cmax = -1e30f;
      #pragma unroll
      for (int mi=0;mi<4;mi++)
        #pragma unroll
        for (int r=0;r<4;r++){
          float x = sacc[mi][r] * 8.f;
          if (!interior){
            int j = jlo + mi*16 + g*4 + r;
            int ql = wq + qi;
            if (j < ql || j > ql+256) x = -1e30f;
          }
          sacc[mi][r] = x;
          cmax = fmaxf(cmax, x);
        }
      cmax = fmaxf(cmax, __shfl_xor(cmax,16,64));
      cmax = fmaxf(cmax, __shfl_xor(cmax,32,64));
      float mn = fmaxf(mrun, cmax);
      float scl = __expf(mrun - mn);
      mrun = mn;
      float ps = 0.f;
      s16x8 pf[2];
      #pragma unroll
      for (int t=0;t<2;t++)
        #pragma unroll
        for (int hh=0; hh<2; hh++){
          int mi = 2*t+hh;
          #pragma unroll
          for (int r=0;r<4;r++){
            float pv = __expf(sacc[mi][r]-mn);
            ps += pv;
            pf[t][hh*4+r] = f2bf(pv);
          }
        }
      ps += __shfl_xor(ps,16,64);
      ps += __shfl_xor(ps,32,64);
      lrun = lrun*scl + ps;
      #pragma unroll
      for (int mi=0;mi<4;mi++) oacc[mi] *= scl;
      #pragma unroll
      for (int t=0;t<2;t++)
        #pragma unroll
        for (int mi=0;mi<4;mi++){
          const short* vp = &Vs[mi*16+qi][cc*64 + t*32 + g*4];
          s16x4 lo = *(const s16x4*)vp;
          s16x4 hi = *(const s16x4*)(vp+16);
          s16x8 vf = {lo[0],lo[1],lo[2],lo[3],hi[0],hi[1],hi[2],hi[3]};
          oacc[mi] = MFMA(vf, pf[t], oacc[mi]);
        }
    }
  }
  float inv = 1.f / lrun;
  #pragma unroll
  for (int mi=0;mi<4;mi++){
    s16x4 st;
    #pragma unroll
    for (int r=0;r<4;r++) st[r] = f2bf(oacc[mi][r]*inv);
    *(s16x4*)(attn_o + (size_t)(q0abs+qi)*512 + h*64 + mi*16 + g*4) = st;
  }
}

extern "C" void kernel_launch(void* const* d_in, const int* in_sizes, int n_in,
                              void* d_out, int out_size, void* d_ws, size_t ws_size,
                              hipStream_t stream)
{
  const float* x_in = (const float*)d_in[0];
  const float* Wqkv = (const float*)d_in[1];
  const float* Wo   = (const float*)d_in[2];
  const float* qsc  = (const float*)d_in[3];
  const float* ksc  = (const float*)d_in[4];
  const float* W1   = (const float*)d_in[5];
  const float* b1   = (const float*)d_in[6];
  const float* W2   = (const float*)d_in[7];
  const float* b2   = (const float*)d_in[8];
  float* xf = (float*)d_out;

  char* ws = (char*)d_ws;
  size_t off = 0;
  float* tab  = (float*)(ws + off); off += (size_t)4*8192*64*4;
  short* WqkvT= (short*)(ws + off); off += (size_t)6*1536*512*2;
  short* WoT  = (short*)(ws + off); off += (size_t)6*512*512*2;
  short* W1T  = (short*)(ws + off); off += (size_t)6*2730*512*2;
  short* W2T  = (short*)(ws + off); off += (size_t)6*512*1376*2;
  short* xbf  = (short*)(ws + off); off += (size_t)8192*512*2;
  short* qrot = (short*)(ws + off); off += (size_t)8*8192*64*2;
  short* krot = (short*)(ws + off); off += (size_t)8*8192*64*2;
  short* vt   = (short*)(ws + off); off += (size_t)8*8192*64*2;
  short* attno= (short*)(ws + off); off += (size_t)8192*512*2;
  short* hg   = (short*)(ws + off); off += (size_t)8192*1376*2;

  hipMemcpyAsync(xf, x_in, (size_t)8192*512*4, hipMemcpyDeviceToDevice, stream);
  rope_k<<<8192, 64, 0, stream>>>(tab);
  wtrans_k<<<dim3(24,8,6),256,0,stream>>>(Wqkv, WqkvT, 512,1536,512, (long)512*1536, (long)1536*512);
  wtrans_k<<<dim3(8,8,6),256,0,stream>>>(Wo, WoT, 512,512,512, (long)512*512,(long)512*512);
  wtrans_k<<<dim3(43,8,6),256,0,stream>>>(W1, W1T, 512,2730,512, (long)512*2730,(long)2730*512);
  wtrans_k<<<dim3(8,22,6),256,0,stream>>>(W2, W2T, 1365,512,1376, (long)1365*512,(long)512*1376);
  cast_k<<<4096,256,0,stream>>>(x_in, xbf);

  for (int l=0;l<6;l++){
    qkv_fused_k<<<dim3(64,12),512,0,stream>>>(xbf, WqkvT + (size_t)l*1536*512,
        tab, qsc + l*64, ksc + l*64, qrot, krot, vt);
    attn_k<<<dim3(64,8),512,0,stream>>>(qrot, krot, vt, attno);
    gemm128x64_k<0,1,1,1><<<dim3(64,8),256,0,stream>>>(attno, WoT + (size_t)l*512*512,
        nullptr, xf, xf, xbf, 8192,512,512);
    geglu_k<<<dim3(64,11),512,0,stream>>>(xbf, W1T + (size_t)l*2730*512, b1 + (size_t)l*2730, hg);
    gemm128x64_k<1,1,1,1><<<dim3(64,8),256,0,stream>>>(hg, W2T + (size_t)l*512*1376,
        b2 + (size_t)l*512, xf, xf, xbf, 8192,512,1376);
  }
}